// Round 7
// baseline (463.177 us; speedup 1.0000x reference)
//
#include <hip/hip_runtime.h>
#include <hip/hip_bf16.h>
#include <stdint.h>
#include <stddef.h>

// Dims (fixed): B=4096 L=64 H=512 E=256 T=256 S=128 CT=259 R=4096 V=256 IN=1670
// x layout: [a_tm1(256) | p_t(768) | n_t(128) | ctx_env(259) | ctx_lc(259)] = 1670 pad 1696
#define XP 1696
#define KC 288   // CT=259 padded to 9*32
#define EP 264   // emb LDS row stride (u16): 528B rows, 16B-aligned

// --- ctx group schedule geometry ---
#define BIG_G   8192
#define TWO_G   4096
#define ONE_G   2048
#define N_GROUP (BIG_G + TWO_G + ONE_G)
#define N_SLOTI (N_GROUP * 4)

typedef __attribute__((ext_vector_type(8))) short bf16x8;
typedef __attribute__((ext_vector_type(4))) float f32x4;

__device__ __forceinline__ unsigned short f32_bf16(float f) {
    union { float f; unsigned int u; } v; v.f = f;
    unsigned int r = v.u + 0x7FFFu + ((v.u >> 16) & 1u);
    return (unsigned short)(r >> 16);
}
__device__ __forceinline__ unsigned int bf_rnd(float f) {   // rounded bits in [31:16]
    union { float f; unsigned int u; } v; v.f = f;
    return v.u + 0x7FFFu + ((v.u >> 16) & 1u);
}
__device__ __forceinline__ float bf16_f32(unsigned short u) {
    union { unsigned int u; float f; } v; v.u = ((unsigned int)u) << 16;
    return v.f;
}

// ---------------- tiled transpose-pack: dst[n][k] = bf16(src[k][n]), k>=Ksrc -> 0 ----
// grid: (ceil(Nsrc/64), ceil(Kp/64)), block 256. Coalesced loads AND stores.
__global__ void tpack_kernel(const float* __restrict__ src, unsigned short* __restrict__ dst,
                             int Ksrc, int Nsrc, int Kp) {
    __shared__ float t[64][65];
    const int tid = threadIdx.x;
    const int n0 = blockIdx.x * 64, k0 = blockIdx.y * 64;
    const int ln = tid & 63;
    const int g  = tid >> 6;
    #pragma unroll
    for (int j = 0; j < 16; j++) {
        int kl = g + j * 4;
        int k = k0 + kl, n = n0 + ln;
        float v = 0.f;
        if (k < Ksrc && n < Nsrc) v = src[(size_t)k * Nsrc + n];
        t[kl][ln] = v;
    }
    __syncthreads();
    #pragma unroll
    for (int j = 0; j < 16; j++) {
        int nl = g + j * 4;
        int n = n0 + nl, k = k0 + ln;
        if (n < Nsrc && k < Kp) dst[(size_t)n * Kp + k] = f32_bf16(t[ln][nl]);
    }
}

__global__ void cvt_kernel(const float* __restrict__ src, unsigned short* __restrict__ dst, int total) {
    int idx = blockIdx.x * blockDim.x + threadIdx.x;
    if (idx < total) dst[idx] = f32_bf16(src[idx]);
}

// x base assembly: a_tm1 | p_t | n_t gather | (ctx written later) | zero pad
__global__ void xasm_kernel(const float* __restrict__ a_tm1, const float* __restrict__ p_t,
                            const int* __restrict__ sym, const float* __restrict__ symtab,
                            unsigned short* __restrict__ x_out) {
    int idx = blockIdx.x * blockDim.x + threadIdx.x;
    if (idx >= 4096 * XP) return;
    int b = idx / XP, c = idx - b * XP;
    float v;
    if (c < 256)       v = a_tm1[(size_t)b * 256 + c];
    else if (c < 1024) v = p_t[(size_t)b * 768 + (c - 256)];
    else if (c < 1152) v = symtab[(size_t)sym[b] * 128 + (c - 1024)];
    else if (c < 1670) return;           // ctx slices written by ctx_kernel
    else v = 0.0f;                        // pad 1670..1695
    x_out[idx] = f32_bf16(v);
}

// ---------------- ctx schedule: init + build ----------------
__global__ void sinit_kernel(int* __restrict__ s) {
    int i = blockIdx.x * 256 + threadIdx.x;
    if (i < N_SLOTI) s[i] = -1;
    else if (i < N_SLOTI + 3) s[i] = 0;
}

// item idx in [0,8192): b=idx>>1, which=idx&1. m'=max(ceil(len/16),1), clamp 4.
// slot content = idx*4 + tile_index; item's tiles are consecutive slots, never
// crossing a group boundary; head tile has (d&3)==0.
__global__ void sched_kernel(const int* __restrict__ len_env, const int* __restrict__ len_lc,
                             int* __restrict__ slots) {
    int idx = blockIdx.x * blockDim.x + threadIdx.x;
    if (idx >= 8192) return;
    int b = idx >> 1, wh = idx & 1;
    int len = wh ? len_lc[b] : len_env[b];
    int m = (len + 15) >> 4;
    if (m == 0) m = 1;
    if (m > 4) m = 4;
    int* cursors = slots + N_SLOTI;
    int base;
    if (m >= 3)      { int p = atomicAdd(&cursors[0], 1); base = p * 4; }
    else if (m == 2) { int p = atomicAdd(&cursors[1], 1); base = BIG_G * 4 + (p >> 1) * 4 + (p & 1) * 2; }
    else             { int p = atomicAdd(&cursors[2], 1); base = (BIG_G + TWO_G) * 4 + (p >> 2) * 4 + (p & 3); }
    for (int k = 0; k < m; k++) slots[base + k] = idx * 4 + k;
}

// ---------------- generic GEMM (m97 structure, unchanged) ----------------
template<int ACT, int OUT_BF16>
__global__ __launch_bounds__(256, 2)
void gemm_bt_kernel(const unsigned short* __restrict__ A,
                    const unsigned short* __restrict__ BT,
                    const float* __restrict__ bias,
                    void* __restrict__ Cout,
                    int M, int N, int K)
{
    __shared__ unsigned short a_lds[128 * 32];
    __shared__ unsigned short b_lds[128 * 32];
    const int tid  = threadIdx.x;
    const int lane = tid & 63;
    const int wave = tid >> 6;
    const int wm = wave >> 1, wn = wave & 1;
    const int row0 = blockIdx.y * 128;
    const int col0 = blockIdx.x * 128;

    f32x4 acc[4][4];
    #pragma unroll
    for (int i = 0; i < 4; i++)
        #pragma unroll
        for (int j = 0; j < 4; j++) acc[i][j] = (f32x4){0.f, 0.f, 0.f, 0.f};

    const int fr = lane & 15;
    const int kk = (lane >> 4) * 8;
    const int srow = (lane >> 2);
    const int scol = (lane & 3) * 8;

    for (int k0 = 0; k0 < K; k0 += 32) {
        __syncthreads();
        #pragma unroll
        for (int j = 0; j < 4; j++) {
            const int c = (wave & 1) * 4 + j;
            const unsigned short* gsrc;
            unsigned short* ldst;
            if (wave < 2) {
                gsrc = A  + (size_t)(row0 + c * 16 + srow) * K + k0 + scol;
                ldst = &a_lds[c * 512];
            } else {
                gsrc = BT + (size_t)(col0 + c * 16 + srow) * K + k0 + scol;
                ldst = &b_lds[c * 512];
            }
            __builtin_amdgcn_global_load_lds(
                (const __attribute__((address_space(1))) void*)gsrc,
                (__attribute__((address_space(3))) void*)ldst, 16, 0, 0);
        }
        __syncthreads();

        bf16x8 af[4], bf[4];
        #pragma unroll
        for (int mt = 0; mt < 4; mt++) af[mt] = *(const bf16x8*)&a_lds[(wm * 64 + mt * 16 + fr) * 32 + kk];
        #pragma unroll
        for (int nt = 0; nt < 4; nt++) bf[nt] = *(const bf16x8*)&b_lds[(wn * 64 + nt * 16 + fr) * 32 + kk];
        #pragma unroll
        for (int mt = 0; mt < 4; mt++)
            #pragma unroll
            for (int nt = 0; nt < 4; nt++)
                acc[mt][nt] = __builtin_amdgcn_mfma_f32_16x16x32_bf16(af[mt], bf[nt], acc[mt][nt], 0, 0, 0);
    }

    const int fq = lane >> 4;
    #pragma unroll
    for (int mt = 0; mt < 4; mt++)
        #pragma unroll
        for (int nt = 0; nt < 4; nt++) {
            int cg = col0 + wn * 64 + nt * 16 + fr;
            float bv = bias ? bias[cg] : 0.0f;
            #pragma unroll
            for (int i = 0; i < 4; i++) {
                int rg = row0 + wm * 64 + mt * 16 + fq * 4 + i;
                float v = acc[mt][nt][i] + bv;
                if (ACT == 1) v = tanhf(v);
                if (OUT_BF16) ((unsigned short*)Cout)[(size_t)rg * N + cg] = f32_bf16(v);
                else          ((float*)Cout)[(size_t)rg * N + cg] = v;
            }
        }
}

// ---------------- fused context read (v7: packed LDS + cheap stage + flat wsum) ----------------
__global__ __launch_bounds__(512, 4)
void ctx_kernel(const float* __restrict__ emb_env, const float* __restrict__ emb_lc,
                const int* __restrict__ len_env, const int* __restrict__ len_lc,
                const float* __restrict__ s_proj,          // [B,512] f32 (b1 included)
                const unsigned short* __restrict__ W1eT,   // [512][288] bf16 (zero-padded k>=259)
                const float* __restrict__ W2, const float* __restrict__ b2,
                const int* __restrict__ slots,
                unsigned short* __restrict__ x_out)        // [B][1696] bf16
{
    const int g = blockIdx.x;
    const int4 dv = *reinterpret_cast<const int4*>(slots + (size_t)g * 4);
    if (dv.x < 0) return;
    int d[4] = {dv.x, dv.y, dv.z, dv.w};

    __shared__ unsigned short emb_lds[64 * EP];   // packed, 528B rows
    __shared__ float partial_lds[8][64];
    __shared__ float w_lds[64];
    __shared__ int hinfo0[4], hinfo1[4], hinfo_n;

    const int tid = threadIdx.x;   // 0..511
    const int lane = tid & 63;
    const int wave = tid >> 6;
    const int fr = lane & 15;
    const int fq = lane >> 4;
    const float b2v = b2[0];

    // compact head list (thread 0; covered by the stage barrier)
    if (tid == 0) {
        int n = 0;
        #pragma unroll
        for (int s = 0; s < 4; s++) {
            int dh = d[s];
            if (dh >= 0 && (dh & 3) == 0) {
                int it = dh >> 2;
                int b = it >> 1, wh = it & 1;
                int len = (wh ? len_lc : len_env)[b];
                hinfo0[n] = (s * 16) | (len << 8);
                hinfo1[n] = b * 2 + wh;
                n++;
            }
        }
        hinfo_n = n;
    }

    // zero the 5 K-pad cols (259..263) of every row (needed by the MFMA tail step)
    if (tid < 320) {
        int r = tid / 5, c = 259 + (tid - (tid / 5) * 5);
        emb_lds[r * EP + c] = 0;
    }

    // ---- stage: 128 threads per slot; flat float4 loads, pair-packed bf16 LDS writes ----
    {
        const int sl = tid >> 7;
        const int t  = tid & 127;
        const int ds = d[sl];
        int nrows = 0;
        const float* src = nullptr;
        if (ds >= 0) {
            int it = ds >> 2, tix = ds & 3;
            int b = it >> 1, wh = it & 1;
            int len = (wh ? len_lc : len_env)[b];
            nrows = len - tix * 16;
            if (nrows > 16) nrows = 16;
            if (nrows < 0) nrows = 0;
            src = (wh ? emb_lc : emb_env) + ((size_t)b * 64 + tix * 16) * 259;
        }
        const int nf4 = (nrows * 259 + 3) >> 2;   // <= 1036
        const float4* s4 = reinterpret_cast<const float4*>(src);
        float4 v[9];
        #pragma unroll
        for (int j = 0; j < 9; j++) {
            int q = t + j * 128;
            if (q < nf4) v[j] = s4[q];
        }
        unsigned short* ebase = &emb_lds[sl * 16 * EP];
        #pragma unroll
        for (int j = 0; j < 9; j++) {
            int q = t + j * 128;
            if (q < nf4) {
                int e0 = q * 4;
                int r  = (int)(((unsigned)e0 * 64779u) >> 24);   // e0/259, valid e0<=16575
                int c0 = e0 - r * 259;
                unsigned int u0 = bf_rnd(v[j].x), u1 = bf_rnd(v[j].y);
                unsigned int u2 = bf_rnd(v[j].z), u3 = bf_rnd(v[j].w);
                unsigned short* rp = ebase + r * EP;
                if (c0 <= 255) {
                    if ((c0 & 1) == 0) {
                        *(unsigned int*)(rp + c0)     = __builtin_amdgcn_perm(u1, u0, 0x07060302);
                        *(unsigned int*)(rp + c0 + 2) = __builtin_amdgcn_perm(u3, u2, 0x07060302);
                    } else {
                        rp[c0]     = (unsigned short)(u0 >> 16);
                        *(unsigned int*)(rp + c0 + 1) = __builtin_amdgcn_perm(u2, u1, 0x07060302);
                        rp[c0 + 3] = (unsigned short)(u3 >> 16);
                    }
                } else {
                    // row straddle (c0 in {256,257,258}): per-elem
                    unsigned int uu[4] = {u0, u1, u2, u3};
                    #pragma unroll
                    for (int jj = 0; jj < 4; jj++) {
                        int e = e0 + jj;
                        int r2 = r, c2 = c0 + jj;
                        if (c2 >= 259) { r2 = r + 1; c2 -= 259; }
                        ebase[r2 * EP + c2] = (unsigned short)(uu[jj] >> 16);
                    }
                }
            }
        }
    }
    __syncthreads();

    // ---- MFMA: 4 M-tiles x 4 n-tiles, K=259 as 8 full k-steps + tail ----
    f32x4 acc[4][4];
    #pragma unroll
    for (int i = 0; i < 4; i++)
        #pragma unroll
        for (int j = 0; j < 4; j++) acc[i][j] = (f32x4){0.f, 0.f, 0.f, 0.f};

    #pragma unroll
    for (int ks = 0; ks < 9; ks++) {
        bf16x8 bfr[4];
        #pragma unroll
        for (int nt = 0; nt < 4; nt++) {
            int n = wave * 64 + nt * 16 + fr;
            bfr[nt] = *(const bf16x8*)(W1eT + (size_t)n * KC + ks * 32 + fq * 8);
        }
        bf16x8 af[4];
        if (ks < 8) {
            #pragma unroll
            for (int mt = 0; mt < 4; mt++)
                af[mt] = *(const bf16x8*)&emb_lds[(mt * 16 + fr) * EP + ks * 32 + fq * 8];
        } else {
            // tail: k 256..287. fq==0 covers k 256..263 (259..263 are zeroed pad);
            // fq>=1 would be k>=264 -> all zero.
            #pragma unroll
            for (int mt = 0; mt < 4; mt++) {
                bf16x8 z = {};
                if (fq == 0) z = *(const bf16x8*)&emb_lds[(mt * 16 + fr) * EP + 256];
                af[mt] = z;
            }
        }
        __builtin_amdgcn_s_setprio(1);
        #pragma unroll
        for (int nt = 0; nt < 4; nt++)
            #pragma unroll
            for (int mt = 0; mt < 4; mt++)
                acc[mt][nt] = __builtin_amdgcn_mfma_f32_16x16x32_bf16(af[mt], bfr[nt], acc[mt][nt], 0, 0, 0);
        __builtin_amdgcn_s_setprio(0);
    }

    // ---- epilogue: relu(acc + s_proj[b_of_slot]) * W2 -> per-row logit partials ----
    int bslot[4];
    #pragma unroll
    for (int mt = 0; mt < 4; mt++) bslot[mt] = d[mt] >= 0 ? (d[mt] >> 3) : -1;

    float wv[4];
    #pragma unroll
    for (int nt = 0; nt < 4; nt++) wv[nt] = W2[wave * 64 + nt * 16 + fr];

    float plog[4][4];
    #pragma unroll
    for (int mt = 0; mt < 4; mt++)
        #pragma unroll
        for (int ii = 0; ii < 4; ii++) plog[mt][ii] = 0.f;
    #pragma unroll
    for (int nt = 0; nt < 4; nt++) {
        int n = wave * 64 + nt * 16 + fr;
        #pragma unroll
        for (int mt = 0; mt < 4; mt++) {
            if (bslot[mt] < 0) continue;
            float sp = s_proj[(size_t)bslot[mt] * 512 + n];
            #pragma unroll
            for (int ii = 0; ii < 4; ii++) {
                float h = acc[mt][nt][ii] + sp;
                h = fmaxf(h, 0.f);
                plog[mt][ii] += h * wv[nt];
            }
        }
    }
    #pragma unroll
    for (int mt = 0; mt < 4; mt++) {
        if (bslot[mt] < 0) continue;
        #pragma unroll
        for (int ii = 0; ii < 4; ii++) {
            float v = plog[mt][ii];
            v += __shfl_xor(v, 1); v += __shfl_xor(v, 2);
            v += __shfl_xor(v, 4); v += __shfl_xor(v, 8);
            if (fr == 0) partial_lds[wave][mt * 16 + fq * 4 + ii] = v;
        }
    }
    __syncthreads();

    // ---- per-item softmax: wave v handles slot v if head ----
    if (wave < 4) {
        int dh = d[wave];
        if (dh >= 0 && (dh & 3) == 0) {
            int it = dh >> 2;
            int b = it >> 1, wh = it & 1;
            int len = (wh ? len_lc : len_env)[b];
            int m = (len + 15) >> 4; if (m == 0) m = 1;
            float logit = -1e9f;
            if (lane < 16 * m && lane < len) {
                logit = b2v;
                #pragma unroll
                for (int w = 0; w < 8; w++) logit += partial_lds[w][wave * 16 + lane];
            }
            float mx = logit;
            #pragma unroll
            for (int off = 1; off < 64; off <<= 1) mx = fmaxf(mx, __shfl_xor(mx, off));
            float e = __expf(logit - mx);
            float s = e;
            #pragma unroll
            for (int off = 1; off < 64; off <<= 1) s += __shfl_xor(s, off);
            if (lane < 16 * m) w_lds[wave * 16 + lane] = e / s;
        }
    }
    __syncthreads();

    // ---- wsum flattened over (head, c) across all 512 threads ----
    {
        const int nh = hinfo_n;
        const int total = nh * 259;
        for (int q = tid; q < total; q += 512) {
            int h = (int)(((unsigned)q * 1013u) >> 18);   // q/259, valid q<=1035
            int c = q - h * 259;
            int w0 = hinfo0[h];
            int base = w0 & 0xFF;        // slot*16
            int len = w0 >> 8;
            int w1v = hinfo1[h];
            int b = w1v >> 1, wh = w1v & 1;
            float a0 = 0.f, a1 = 0.f, a2 = 0.f, a3 = 0.f;
            int l = 0;
            for (; l + 3 < len; l += 4) {
                a0 += w_lds[base + l]     * bf16_f32(emb_lds[(base + l) * EP + c]);
                a1 += w_lds[base + l + 1] * bf16_f32(emb_lds[(base + l + 1) * EP + c]);
                a2 += w_lds[base + l + 2] * bf16_f32(emb_lds[(base + l + 2) * EP + c]);
                a3 += w_lds[base + l + 3] * bf16_f32(emb_lds[(base + l + 3) * EP + c]);
            }
            for (; l < len; l++) a0 += w_lds[base + l] * bf16_f32(emb_lds[(base + l) * EP + c]);
            x_out[(size_t)b * XP + (wh ? 1411 : 1152) + c] = f32_bf16((a0 + a1) + (a2 + a3));
        }
    }
}

// ---------------- GRU pointwise ----------------
__global__ void gru_kernel(const float* __restrict__ gx, const float* __restrict__ gh,
                           const float* __restrict__ s, unsigned short* __restrict__ h_b) {
    int idx = blockIdx.x * blockDim.x + threadIdx.x;
    if (idx >= 4096 * 512) return;
    int b = idx >> 9, c = idx & 511;
    const float* gxb = gx + (size_t)b * 1536;
    const float* ghb = gh + (size_t)b * 1536;
    float xr = gxb[c], xz = gxb[c + 512], xn = gxb[c + 1024];
    float hr = ghb[c], hz = ghb[c + 512], hn = ghb[c + 1024];
    float r = 1.f / (1.f + __expf(-(xr + hr)));
    float z = 1.f / (1.f + __expf(-(xz + hz)));
    float n = tanhf(xn + r * hn);
    float h = (1.f - z) * n + z * s[idx];
    h_b[idx] = f32_bf16(h);
}

// ---------------- host ----------------
extern "C" void kernel_launch(void* const* d_in, const int* in_sizes, int n_in,
                              void* d_out, int out_size, void* d_ws, size_t ws_size,
                              hipStream_t stream) {
    const float* s_tm1   = (const float*)d_in[0];
    const float* a_tm1   = (const float*)d_in[1];
    const float* p_t     = (const float*)d_in[2];
    const int*   sym     = (const int*)d_in[3];
    const float* env_emb = (const float*)d_in[4];
    const int*   env_len = (const int*)d_in[5];
    const float* lc_emb  = (const float*)d_in[6];
    const int*   lc_len  = (const int*)d_in[7];
    const float* symtab  = (const float*)d_in[8];
    const float* W1      = (const float*)d_in[9];
    const float* b1      = (const float*)d_in[10];
    const float* W2      = (const float*)d_in[11];
    const float* b2      = (const float*)d_in[12];
    const float* W_ih    = (const float*)d_in[13];
    const float* W_hh    = (const float*)d_in[14];
    const float* b_ih    = (const float*)d_in[15];
    const float* b_hh    = (const float*)d_in[16];
    const float* Wd      = (const float*)d_in[17];
    const float* bd      = (const float*)d_in[18];
    const float* rule    = (const float*)d_in[19];

    // ws layout (~43 MB)
    char* w = (char*)d_ws;
    float* s_proj = (float*)w;              w += (size_t)4096 * 512 * 4;
    unsigned short* W1sT  = (unsigned short*)w; w += (size_t)512 * 512 * 2;
    unsigned short* W1eT  = (unsigned short*)w; w += (size_t)512 * KC * 2;
    unsigned short* WihT  = (unsigned short*)w; w += (size_t)1536 * XP * 2;
    unsigned short* WhhT  = (unsigned short*)w; w += (size_t)1536 * 512 * 2;
    unsigned short* WdT   = (unsigned short*)w; w += (size_t)256 * 512 * 2;
    unsigned short* ruleb = (unsigned short*)w; w += (size_t)4096 * 256 * 2;
    unsigned short* s_b   = (unsigned short*)w; w += (size_t)4096 * 512 * 2;
    unsigned short* x_b   = (unsigned short*)w; w += (size_t)4096 * XP * 2;
    unsigned short* h_b   = (unsigned short*)w; w += (size_t)4096 * 512 * 2;
    unsigned short* dec_b = (unsigned short*)w; w += (size_t)4096 * 256 * 2;
    int* slots = (int*)w;                   w += (size_t)(N_SLOTI + 8) * 4;

    float* out_f = (float*)d_out;
    float* gx = out_f;                        // [4096][1536]
    float* gh = out_f + (size_t)4096 * 1536;  // [4096][1536]

    // --- schedule init/build ---
    sinit_kernel<<<(N_SLOTI + 3 + 255) / 256, 256, 0, stream>>>(slots);
    sched_kernel<<<32, 256, 0, stream>>>(env_len, lc_len, slots);

    // --- packs (tiled transpose) ---
    tpack_kernel<<<dim3(8, 8),   256, 0, stream>>>(W1, W1sT, 512, 512, 512);
    tpack_kernel<<<dim3(8, 5),   256, 0, stream>>>(W1 + (size_t)512 * 512, W1eT, 259, 512, KC);
    tpack_kernel<<<dim3(24, 27), 256, 0, stream>>>(W_ih, WihT, 1670, 1536, XP);
    tpack_kernel<<<dim3(24, 8),  256, 0, stream>>>(W_hh, WhhT, 512, 1536, 512);
    tpack_kernel<<<dim3(4, 8),   256, 0, stream>>>(Wd, WdT, 512, 256, 512);
    cvt_kernel<<<4096, 256, 0, stream>>>(rule, ruleb, 4096 * 256);
    cvt_kernel<<<8192, 256, 0, stream>>>(s_tm1, s_b, 4096 * 512);
    xasm_kernel<<<(4096 * XP + 255) / 256, 256, 0, stream>>>(a_tm1, p_t, sym, symtab, x_b);

    // s_proj = s_tm1 @ W1[:512] + b1
    gemm_bt_kernel<0, 0><<<dim3(4, 32), 256, 0, stream>>>(s_b, W1sT, b1, s_proj, 4096, 512, 512);

    // fused context reads -> x slices (bin-packed groups)
    ctx_kernel<<<N_GROUP, 512, 0, stream>>>(env_emb, lc_emb, env_len, lc_len,
                                            s_proj, W1eT, W2, b2, slots, x_b);

    // GRU gates
    gemm_bt_kernel<0, 0><<<dim3(12, 32), 256, 0, stream>>>(x_b, WihT, b_ih, gx, 4096, 1536, XP);
    gemm_bt_kernel<0, 0><<<dim3(12, 32), 256, 0, stream>>>(s_b, WhhT, b_hh, gh, 4096, 1536, 512);
    gru_kernel<<<8192, 256, 0, stream>>>(gx, gh, s_tm1, h_b);

    // dec = tanh(h @ Wd + bd)  (bf16 out)
    gemm_bt_kernel<1, 1><<<dim3(2, 32), 256, 0, stream>>>(h_b, WdT, bd, dec_b, 4096, 256, 512);

    // logits = dec @ rule^T
    gemm_bt_kernel<0, 0><<<dim3(32, 32), 256, 0, stream>>>(dec_b, ruleb, nullptr, out_f, 4096, 4096, 256);
}